// Round 8
// baseline (326.996 us; speedup 1.0000x reference)
//
#include <hip/hip_runtime.h>
#include <float.h>
#include <math.h>

#define B_NUM 64
#define P_NUM 8732
#define T_NUM 16
#define C_NUM 81
#define TPB   512
#define RPB_LSE 128
#define NBLK_LSE ((B_NUM * P_NUM) / RPB_LSE)   // 4366
#define GRID  (B_NUM + NBLK_LSE)               // 4430
#define ELEMS 18                               // ceil(8732/512)

__device__ __forceinline__ float smooth_l1(float d) {
    float ad = fabsf(d);
    return (ad < 1.0f) ? 0.5f * d * d : ad - 0.5f;
}

// match/select blocks: ~28 KB ; lse blocks: 41.5 KB -> union 41.5 KB, 3 blk/CU
struct MatchSh {
    float s_t[T_NUM][4];
    int   s_lab[T_NUM];
    unsigned short s_m[P_NUM];   // bit15 = positive flag, low bits = truth idx
    float s_rv[8 * T_NUM];
    int   s_ri[8 * T_NUM];
    int   s_bp[T_NUM];
    float s_red[8];
    int   s_redi[8];
    int   s_wh[8][256];          // wave-private histograms (8 KB)
    int   s_hist[256];
    int   s_sel, s_rem, s_np, s_last;
    float s_sv[8]; int s_sc[8]; float s_pv[8];
};
struct LseSh { float s_c[RPB_LSE * C_NUM]; };  // 128*81*4 = 41.5 KB
union __align__(16) Sh { MatchSh m; LseSh l; };

__global__ __launch_bounds__(TPB, 4) void k_all(
    const float* __restrict__ loc, const float* __restrict__ conf,
    const float* __restrict__ priors, const float* __restrict__ truths,
    const int* __restrict__ labels,
    int* __restrict__ bctr, int* __restrict__ sel_ctr,
    int* __restrict__ num_pos_g, float* __restrict__ loss_l_b,
    float* __restrict__ negsum_b, float* __restrict__ pce_b,
    float* __restrict__ lse, float* __restrict__ negce,
    float* __restrict__ out)
{
    __shared__ Sh sh;
    const int tid = threadIdx.x;
    const int lane = tid & 63, wv = tid >> 6;

    if (blockIdx.x >= B_NUM) {
        // ================= LSE role (independent of matching) =================
        const int blk = blockIdx.x - B_NUM;
        const int r0 = blk * RPB_LSE;

        const float4* src = (const float4*)(conf + (size_t)r0 * C_NUM);
        float4* dst = (float4*)sh.l.s_c;
#pragma unroll 2
        for (int i = tid; i < (RPB_LSE * C_NUM) / 4; i += TPB) dst[i] = src[i];
        __syncthreads();

        const int row = tid >> 2, sub = tid & 3;
        const int st = sub * 21, en = (sub == 3) ? C_NUM : (st + 21);
        const float* rp = sh.l.s_c + row * C_NUM;

        float m = -FLT_MAX;
        for (int j = st; j < en; ++j) m = fmaxf(m, rp[j]);
        m = fmaxf(m, __shfl_xor(m, 1));
        m = fmaxf(m, __shfl_xor(m, 2));

        float s = 0.0f;
        for (int j = st; j < en; ++j) s += __expf(rp[j] - m);
        s += __shfl_xor(s, 1);
        s += __shfl_xor(s, 2);

        if (sub == 0) {
            int r = r0 + row;
            float l = m + __logf(s);
            lse[r] = l;
            negce[r] = l - rp[0];     // CE when target class = 0 (negatives)
        }
        __syncthreads();              // drains vmcnt -> stores complete
        if (tid == 0) {
            __threadfence();          // publish device-wide
            int b0 = r0 / P_NUM;
            int b1 = (r0 + RPB_LSE - 1) / P_NUM;
            if (b0 == b1) {
                __hip_atomic_fetch_add(&bctr[b0], RPB_LSE,
                                       __ATOMIC_RELEASE, __HIP_MEMORY_SCOPE_AGENT);
            } else {
                int cnt0 = (b0 + 1) * P_NUM - r0;
                __hip_atomic_fetch_add(&bctr[b0], cnt0,
                                       __ATOMIC_RELEASE, __HIP_MEMORY_SCOPE_AGENT);
                __hip_atomic_fetch_add(&bctr[b1], RPB_LSE - cnt0,
                                       __ATOMIC_RELEASE, __HIP_MEMORY_SCOPE_AGENT);
            }
        }
        return;
    }

    // ==================== MATCH + SELECT role (blocks 0..63) ====================
    const int b = blockIdx.x;

    if (tid < T_NUM * 4) ((float*)sh.m.s_t)[tid] = truths[b * T_NUM * 4 + tid];
    if (tid < T_NUM)     sh.m.s_lab[tid] = labels[b * T_NUM + tid];
    __syncthreads();

    // ---- phase A: per-prior best truth; per-thread best prior per truth ----
    float bpv[T_NUM]; int bpi[T_NUM];
#pragma unroll
    for (int t = 0; t < T_NUM; ++t) { bpv[t] = -1.0f; bpi[t] = 0; }

    const float4* pr4 = (const float4*)priors;
    for (int p = tid; p < P_NUM; p += TPB) {
        float4 pr = pr4[p];
        float px0 = pr.x - 0.5f * pr.z, py0 = pr.y - 0.5f * pr.w;
        float px1 = pr.x + 0.5f * pr.z, py1 = pr.y + 0.5f * pr.w;
        float btv = -1.0f; int bti = 0;
#pragma unroll
        for (int t = 0; t < T_NUM; ++t) {
            float ix = fminf(sh.m.s_t[t][2], px1) - fmaxf(sh.m.s_t[t][0], px0);
            float iy = fminf(sh.m.s_t[t][3], py1) - fmaxf(sh.m.s_t[t][1], py0);
            ix = fmaxf(ix, 0.0f); iy = fmaxf(iy, 0.0f);
            float ov = ix * iy;
            if (ov > btv) { btv = ov; bti = t; }          // first max over t
            if (ov > bpv[t]) { bpv[t] = ov; bpi[t] = p; } // first max over p
        }
        // positive iff overlap >= 0.5 (pre-force); forced set below
        sh.m.s_m[p] = (unsigned short)((btv >= 0.5f ? 0x8000 : 0) | bti);
    }
    __syncthreads();

    // ---- reduce best prior per truth: (max val, min idx on tie) ----
#pragma unroll
    for (int t = 0; t < T_NUM; ++t) {
        float v = bpv[t]; int i = bpi[t];
#pragma unroll
        for (int off = 32; off > 0; off >>= 1) {
            float ov = __shfl_down(v, off);
            int   oi = __shfl_down(i, off);
            if (ov > v || (ov == v && oi < i)) { v = ov; i = oi; }
        }
        if (lane == 0) { sh.m.s_rv[wv * T_NUM + t] = v; sh.m.s_ri[wv * T_NUM + t] = i; }
    }
    __syncthreads();
    if (tid < T_NUM) {
        float v = sh.m.s_rv[tid]; int i = sh.m.s_ri[tid];
        for (int w = 1; w < 8; ++w) {
            float ov = sh.m.s_rv[w * T_NUM + tid]; int oi = sh.m.s_ri[w * T_NUM + tid];
            if (ov > v || (ov == v && oi < i)) { v = ov; i = oi; }
        }
        sh.m.s_bp[tid] = i;
    }
    __syncthreads();
    // forced assignment: serial over t, last t wins (matches last_j semantics)
    if (tid == 0) {
        for (int t = 0; t < T_NUM; ++t)
            sh.m.s_m[sh.m.s_bp[t]] = (unsigned short)(0x8000 | t);
    }
    __syncthreads();

    // ---- phase B: num_pos + loc smooth-L1 over positives ----
    int cnt = 0; float lsum = 0.0f;
    const float4* loc4 = (const float4*)loc;
    for (int p = tid; p < P_NUM; p += TPB) {
        unsigned short mm = sh.m.s_m[p];
        if (mm & 0x8000) {
            int ti = mm & 0x7FFF;
            cnt++;
            float4 pr = pr4[p];
            float mx0 = sh.m.s_t[ti][0], my0 = sh.m.s_t[ti][1];
            float mx1 = sh.m.s_t[ti][2], my1 = sh.m.s_t[ti][3];
            float gx = ((mx0 + mx1) * 0.5f - pr.x) / (0.1f * pr.z);
            float gy = ((my0 + my1) * 0.5f - pr.y) / (0.1f * pr.w);
            float gw = __logf((mx1 - mx0) / pr.z + 1e-10f) / 0.2f;
            float gh = __logf((my1 - my0) / pr.w + 1e-10f) / 0.2f;
            float4 l = loc4[(size_t)b * P_NUM + p];
            lsum += smooth_l1(l.x - gx) + smooth_l1(l.y - gy)
                  + smooth_l1(l.z - gw) + smooth_l1(l.w - gh);
        }
    }
#pragma unroll
    for (int off = 32; off > 0; off >>= 1) {
        lsum += __shfl_down(lsum, off);
        cnt  += __shfl_down(cnt, off);
    }
    if (lane == 0) { sh.m.s_red[wv] = lsum; sh.m.s_redi[wv] = cnt; }
    __syncthreads();
    if (tid == 0) {
        float L = 0.0f; int C2 = 0;
        for (int w = 0; w < 8; ++w) { L += sh.m.s_red[w]; C2 += sh.m.s_redi[w]; }
        sh.m.s_np = C2;
        num_pos_g[b] = C2;
        loss_l_b[b] = L;
    }

    // ---- wait for this batch's lse rows (produced by lse-role blocks) ----
    if (tid == 0) {
        while (__hip_atomic_load(&bctr[b], __ATOMIC_ACQUIRE,
                                 __HIP_MEMORY_SCOPE_AGENT) < P_NUM)
            __builtin_amdgcn_s_sleep(8);
    }
    __syncthreads();
    __threadfence();   // invalidate caches before reading peers' lse/negce

    // ---- load per-prior values; positives -> 0 + accumulate positive CE ----
    unsigned int val[ELEMS];
    float pce = 0.0f;
#pragma unroll
    for (int i = 0; i < ELEMS; ++i) {
        int p = tid + i * TPB;
        unsigned int v = 0u;
        if (p < P_NUM) {
            size_t idx = (size_t)b * P_NUM + p;
            unsigned short mm = sh.m.s_m[p];
            if (mm & 0x8000) {
                int c = sh.m.s_lab[mm & 0x7FFF] + 1;
                pce += lse[idx] - conf[idx * C_NUM + c];
            } else {
                v = __float_as_uint(negce[idx]);
            }
        }
        val[i] = v;
    }

    int np = sh.m.s_np;
    int nn = 3 * np; if (nn > P_NUM - 1) nn = P_NUM - 1;

    float negsum_t0 = 0.0f;   // valid on tid 0
    if (nn > 0) {
        unsigned int prefix = 0;
        int k = nn;
#pragma unroll
        for (int shift = 24; shift >= 0; shift -= 8) {
            for (int i = tid; i < 8 * 256; i += TPB) ((int*)sh.m.s_wh)[i] = 0;
            __syncthreads();
            const unsigned int pmask = (shift == 24) ? 0u : (0xFFFFFFFFu << (shift + 8));
#pragma unroll
            for (int i = 0; i < ELEMS; ++i) {
                unsigned int v = val[i];
                if ((v & pmask) == prefix)
                    atomicAdd(&sh.m.s_wh[wv][(v >> shift) & 0xFF], 1);
            }
            __syncthreads();
            if (tid < 256) {
                int s = 0;
#pragma unroll
                for (int w = 0; w < 8; ++w) s += sh.m.s_wh[w][tid];
                sh.m.s_hist[tid] = s;
            }
            __syncthreads();
            if (wv == 0) {
                int c0 = sh.m.s_hist[4 * lane + 0], c1 = sh.m.s_hist[4 * lane + 1];
                int c2 = sh.m.s_hist[4 * lane + 2], c3 = sh.m.s_hist[4 * lane + 3];
                int t3 = c3, t2 = c2 + t3, t1 = c1 + t2, t0 = c0 + t1;
                int g = t0, G = g;
#pragma unroll
                for (int off = 1; off < 64; off <<= 1) {
                    int o = __shfl_down(G, off);
                    if (lane + off < 64) G += o;
                }
                int above = G - g;
                int suf0 = t0 + above, suf1 = t1 + above;
                int suf2 = t2 + above, suf3 = t3 + above, suf4 = above;
                if (suf0 >= k && suf1 < k) { sh.m.s_sel = 4 * lane + 0; sh.m.s_rem = k - suf1; }
                if (suf1 >= k && suf2 < k) { sh.m.s_sel = 4 * lane + 1; sh.m.s_rem = k - suf2; }
                if (suf2 >= k && suf3 < k) { sh.m.s_sel = 4 * lane + 2; sh.m.s_rem = k - suf3; }
                if (suf3 >= k && suf4 < k) { sh.m.s_sel = 4 * lane + 3; sh.m.s_rem = k - suf4; }
            }
            __syncthreads();
            prefix |= ((unsigned int)sh.m.s_sel) << shift;
            k = sh.m.s_rem;
        }

        float sgt = 0.0f; int cgt = 0;
#pragma unroll
        for (int i = 0; i < ELEMS; ++i) {
            unsigned int v = val[i];
            if (v > prefix) { sgt += __uint_as_float(v); cgt++; }
        }
#pragma unroll
        for (int off = 32; off > 0; off >>= 1) {
            sgt += __shfl_down(sgt, off);
            cgt += __shfl_down(cgt, off);
        }
        if (lane == 0) { sh.m.s_sv[wv] = sgt; sh.m.s_sc[wv] = cgt; }
        __syncthreads();
        if (tid == 0) {
            float S = 0.0f; int Ct = 0;
#pragma unroll
            for (int w = 0; w < 8; ++w) { S += sh.m.s_sv[w]; Ct += sh.m.s_sc[w]; }
            negsum_t0 = S + (float)(nn - Ct) * __uint_as_float(prefix);
        }
    }

    // ---- reduce positive CE across block ----
#pragma unroll
    for (int off = 32; off > 0; off >>= 1) pce += __shfl_down(pce, off);
    if (lane == 0) sh.m.s_pv[wv] = pce;
    __syncthreads();

    if (tid == 0) {
        float PCE = 0.0f;
#pragma unroll
        for (int w = 0; w < 8; ++w) PCE += sh.m.s_pv[w];
        pce_b[b] = PCE;
        negsum_b[b] = negsum_t0;
        __threadfence();
        int old = __hip_atomic_fetch_add(sel_ctr, 1,
                                         __ATOMIC_ACQ_REL, __HIP_MEMORY_SCOPE_AGENT);
        sh.m.s_last = (old == B_NUM - 1) ? 1 : 0;
    }
    __syncthreads();

    // ---- last finisher: final reduction over 64 batches (fits in wave 0) ----
    if (sh.m.s_last && wv == 0) {
        __threadfence();
        float ll = loss_l_b[lane];
        float ns = negsum_b[lane];
        float pc = pce_b[lane];
        int   npg = num_pos_g[lane];
#pragma unroll
        for (int off = 32; off > 0; off >>= 1) {
            ll += __shfl_down(ll, off);
            ns += __shfl_down(ns, off);
            pc += __shfl_down(pc, off);
            npg += __shfl_down(npg, off);
        }
        if (lane == 0) {
            float N = (float)(npg > 1 ? npg : 1);
            out[0] = ll / N;
            out[1] = (pc + ns) / N;
        }
    }
}

// ---------------------------------------------------------------------------
extern "C" void kernel_launch(void* const* d_in, const int* in_sizes, int n_in,
                              void* d_out, int out_size, void* d_ws, size_t ws_size,
                              hipStream_t stream) {
    const float* loc    = (const float*)d_in[0];
    const float* conf   = (const float*)d_in[1];
    const float* priors = (const float*)d_in[2];
    const float* truths = (const float*)d_in[3];
    const int*   labels = (const int*)d_in[4];
    float* out = (float*)d_out;

    int*   ws_i = (int*)d_ws;
    float* ws_f = (float*)d_ws;
    int*   bctr      = ws_i;                          // [0,64)
    int*   sel_ctr   = ws_i + 64;                     // [64]
    float* loss_l_b  = ws_f + 128;                    // [128,192)
    float* negsum_b  = ws_f + 192;                    // [192,256)
    float* pce_b     = ws_f + 256;                    // [256,320)
    int*   num_pos_g = ws_i + 320;                    // [320,384)
    float* negce     = ws_f + 512;                    // [512, 512+BP)
    float* lse       = ws_f + 512 + B_NUM * P_NUM;    // [+BP, +2BP)

    // zero the completion counters (graph-capturable, stream-ordered)
    hipMemsetAsync(d_ws, 0, 68 * sizeof(int), stream);

    k_all<<<GRID, TPB, 0, stream>>>(loc, conf, priors, truths, labels,
                                    bctr, sel_ctr, num_pos_g, loss_l_b,
                                    negsum_b, pce_b, lse, negce, out);
}

// Round 9
// 65.085 us; speedup vs baseline: 5.0241x; 5.0241x over previous
//
#include <hip/hip_runtime.h>
#include <float.h>
#include <math.h>

#define B_NUM 64
#define P_NUM 8732
#define T_NUM 16
#define C_NUM 81
#define TPB   512
#define RPB_LSE (TPB / 4)                       // 128 rows per lse block
#define NBLK_LSE ((B_NUM * P_NUM) / RPB_LSE)    // 4366
#define GRID1 (B_NUM + NBLK_LSE)                // 4430

__device__ __forceinline__ float smooth_l1(float d) {
    float ad = fabsf(d);
    return (ad < 1.0f) ? 0.5f * d * d : ad - 0.5f;
}

// alignment-safe 16B load (row bases are only 4B-aligned since 81*4=324)
__device__ __forceinline__ float4 ldg4(const float* p) {
    float4 v; __builtin_memcpy(&v, p, 16); return v;
}

// match blocks' LDS (~19 KB) -> 4 blocks/CU for all blocks
struct MatchSh {
    float s_t[T_NUM][4];
    int   s_lab[T_NUM];
    unsigned short s_m[P_NUM];   // bit15 = positive flag, low bits = truth idx
    float s_rv[8 * T_NUM];
    int   s_ri[8 * T_NUM];
    int   s_bp[T_NUM];
    float s_red[8];
    int   s_redi[8];
};

// ---------------------------------------------------------------------------
// K1 fused: blocks [0,64) = matching (+conf_t write, loc loss, sel_ctr reset);
//           blocks [64,4430) = register-resident lse+negce (NO LDS staging).
// ---------------------------------------------------------------------------
__global__ __launch_bounds__(TPB, 4) void k_fused1(
    const float* __restrict__ loc, const float* __restrict__ conf,
    const float* __restrict__ priors, const float* __restrict__ truths,
    const int* __restrict__ labels,
    int* __restrict__ conf_t, int* __restrict__ num_pos,
    float* __restrict__ loss_l_b, float* __restrict__ lse,
    float* __restrict__ negce, int* __restrict__ sel_ctr)
{
    __shared__ MatchSh shm;
    const int tid = threadIdx.x;
    const int lane = tid & 63, wv = tid >> 6;

    if (blockIdx.x >= B_NUM) {
        // ============ LSE role: registers only, 4 lanes per row ============
        const int r = (blockIdx.x - B_NUM) * RPB_LSE + (tid >> 2);
        const int sub = tid & 3;
        const float* rp = conf + (size_t)r * C_NUM;
        const float* q = rp + sub * 20;          // 20/20/20/21 split, 16B-aligned

        float4 q0 = ldg4(q);
        float4 q1 = ldg4(q + 4);
        float4 q2 = ldg4(q + 8);
        float4 q3 = ldg4(q + 12);
        float4 q4 = ldg4(q + 16);
        float e20 = (sub == 3) ? rp[80] : -FLT_MAX;

        float m = fmaxf(fmaxf(fmaxf(q0.x, q0.y), fmaxf(q0.z, q0.w)),
                        fmaxf(fmaxf(q1.x, q1.y), fmaxf(q1.z, q1.w)));
        m = fmaxf(m, fmaxf(fmaxf(q2.x, q2.y), fmaxf(q2.z, q2.w)));
        m = fmaxf(m, fmaxf(fmaxf(q3.x, q3.y), fmaxf(q3.z, q3.w)));
        m = fmaxf(m, fmaxf(fmaxf(q4.x, q4.y), fmaxf(q4.z, q4.w)));
        m = fmaxf(m, e20);
        m = fmaxf(m, __shfl_xor(m, 1));
        m = fmaxf(m, __shfl_xor(m, 2));

        float s = __expf(q0.x - m) + __expf(q0.y - m) + __expf(q0.z - m) + __expf(q0.w - m)
                + __expf(q1.x - m) + __expf(q1.y - m) + __expf(q1.z - m) + __expf(q1.w - m)
                + __expf(q2.x - m) + __expf(q2.y - m) + __expf(q2.z - m) + __expf(q2.w - m)
                + __expf(q3.x - m) + __expf(q3.y - m) + __expf(q3.z - m) + __expf(q3.w - m)
                + __expf(q4.x - m) + __expf(q4.y - m) + __expf(q4.z - m) + __expf(q4.w - m);
        if (sub == 3) s += __expf(e20 - m);
        s += __shfl_xor(s, 1);
        s += __shfl_xor(s, 2);

        if (sub == 0) {
            float l = m + __logf(s);
            lse[r] = l;
            negce[r] = l - q0.x;     // CE when target class = 0 (negatives)
        }
        return;
    }

    // ==================== MATCH role (blocks 0..63) ====================
    const int b = blockIdx.x;
    if (b == 0 && tid == 0) *sel_ctr = 0;   // reset K2's completion counter

    if (tid < T_NUM * 4) ((float*)shm.s_t)[tid] = truths[b * T_NUM * 4 + tid];
    if (tid < T_NUM)     shm.s_lab[tid] = labels[b * T_NUM + tid];
    __syncthreads();

    float bpv[T_NUM]; int bpi[T_NUM];
#pragma unroll
    for (int t = 0; t < T_NUM; ++t) { bpv[t] = -1.0f; bpi[t] = 0; }

    const float4* pr4 = (const float4*)priors;
    for (int p = tid; p < P_NUM; p += TPB) {
        float4 pr = pr4[p];
        float px0 = pr.x - 0.5f * pr.z, py0 = pr.y - 0.5f * pr.w;
        float px1 = pr.x + 0.5f * pr.z, py1 = pr.y + 0.5f * pr.w;
        float btv = -1.0f; int bti = 0;
#pragma unroll
        for (int t = 0; t < T_NUM; ++t) {
            float ix = fminf(shm.s_t[t][2], px1) - fmaxf(shm.s_t[t][0], px0);
            float iy = fminf(shm.s_t[t][3], py1) - fmaxf(shm.s_t[t][1], py0);
            ix = fmaxf(ix, 0.0f); iy = fmaxf(iy, 0.0f);
            float ov = ix * iy;
            if (ov > btv) { btv = ov; bti = t; }          // first max over t
            if (ov > bpv[t]) { bpv[t] = ov; bpi[t] = p; } // first max over p
        }
        shm.s_m[p] = (unsigned short)((btv >= 0.5f ? 0x8000 : 0) | bti);
    }
    __syncthreads();

    // reduce best prior per truth: (max val, min idx on tie)
#pragma unroll
    for (int t = 0; t < T_NUM; ++t) {
        float v = bpv[t]; int i = bpi[t];
#pragma unroll
        for (int off = 32; off > 0; off >>= 1) {
            float ov = __shfl_down(v, off);
            int   oi = __shfl_down(i, off);
            if (ov > v || (ov == v && oi < i)) { v = ov; i = oi; }
        }
        if (lane == 0) { shm.s_rv[wv * T_NUM + t] = v; shm.s_ri[wv * T_NUM + t] = i; }
    }
    __syncthreads();
    if (tid < T_NUM) {
        float v = shm.s_rv[tid]; int i = shm.s_ri[tid];
        for (int w = 1; w < 8; ++w) {
            float ov = shm.s_rv[w * T_NUM + tid]; int oi = shm.s_ri[w * T_NUM + tid];
            if (ov > v || (ov == v && oi < i)) { v = ov; i = oi; }
        }
        shm.s_bp[tid] = i;
    }
    __syncthreads();
    // forced assignment: serial over t, last t wins (matches last_j semantics)
    if (tid == 0) {
        for (int t = 0; t < T_NUM; ++t)
            shm.s_m[shm.s_bp[t]] = (unsigned short)(0x8000 | t);
    }
    __syncthreads();

    // conf_t + num_pos + loc smooth-L1 over positives
    int cnt = 0; float lsum = 0.0f;
    const float4* loc4 = (const float4*)loc;
    for (int p = tid; p < P_NUM; p += TPB) {
        unsigned short mm = shm.s_m[p];
        int ti = mm & 0x7FFF;
        int c = (mm & 0x8000) ? (shm.s_lab[ti] + 1) : 0;
        conf_t[(size_t)b * P_NUM + p] = c;
        if (c > 0) {
            cnt++;
            float4 pr = pr4[p];
            float mx0 = shm.s_t[ti][0], my0 = shm.s_t[ti][1];
            float mx1 = shm.s_t[ti][2], my1 = shm.s_t[ti][3];
            float gx = ((mx0 + mx1) * 0.5f - pr.x) / (0.1f * pr.z);
            float gy = ((my0 + my1) * 0.5f - pr.y) / (0.1f * pr.w);
            float gw = __logf((mx1 - mx0) / pr.z + 1e-10f) / 0.2f;
            float gh = __logf((my1 - my0) / pr.w + 1e-10f) / 0.2f;
            float4 l = loc4[(size_t)b * P_NUM + p];
            lsum += smooth_l1(l.x - gx) + smooth_l1(l.y - gy)
                  + smooth_l1(l.z - gw) + smooth_l1(l.w - gh);
        }
    }
#pragma unroll
    for (int off = 32; off > 0; off >>= 1) {
        lsum += __shfl_down(lsum, off);
        cnt  += __shfl_down(cnt, off);
    }
    if (lane == 0) { shm.s_red[wv] = lsum; shm.s_redi[wv] = cnt; }
    __syncthreads();
    if (tid == 0) {
        float L = 0.0f; int C2 = 0;
        for (int w = 0; w < 8; ++w) { L += shm.s_red[w]; C2 += shm.s_redi[w]; }
        num_pos[b] = C2;
        loss_l_b[b] = L;
    }
}

// ---------------------------------------------------------------------------
// K2: per-batch radix-select top-nn sum + positive CE gather + final reduce.
// (proven round-7 version, unchanged)
// ---------------------------------------------------------------------------
#define ELEMS 9  // ceil(8732/1024)

__global__ __launch_bounds__(1024) void k_select(
    const float* __restrict__ negce, const float* __restrict__ lse,
    const float* __restrict__ conf, const int* __restrict__ conf_t,
    const int* __restrict__ num_pos, float* __restrict__ loss_l_b,
    float* __restrict__ negsum_b, float* __restrict__ pce_b,
    int* __restrict__ sel_ctr, float* __restrict__ out)
{
    __shared__ int   s_wh[16][256];   // wave-private histograms (16 KB)
    __shared__ int   s_hist[256];
    __shared__ int   s_sel, s_rem;
    __shared__ float s_sv[16];
    __shared__ int   s_sc[16];
    __shared__ float s_pv[16];
    __shared__ int   s_last;

    const int b = blockIdx.x, tid = threadIdx.x;
    const int lane = tid & 63, wv = tid >> 6;

    unsigned int val[ELEMS];
    float pce = 0.0f;
#pragma unroll
    for (int i = 0; i < ELEMS; ++i) {
        int p = tid + i * 1024;
        unsigned int v = 0u;
        if (p < P_NUM) {
            size_t idx = (size_t)b * P_NUM + p;
            int c = conf_t[idx];
            if (c == 0) {
                v = __float_as_uint(negce[idx]);
            } else {
                pce += lse[idx] - conf[idx * C_NUM + c];
            }
        }
        val[i] = v;
    }

    int np = num_pos[b];
    int nn = 3 * np; if (nn > P_NUM - 1) nn = P_NUM - 1;

    if (nn > 0) {
        unsigned int prefix = 0;
        int k = nn;
#pragma unroll
        for (int shift = 24; shift >= 0; shift -= 8) {
            for (int i = tid; i < 16 * 256; i += 1024) ((int*)s_wh)[i] = 0;
            __syncthreads();
            const unsigned int pmask = (shift == 24) ? 0u : (0xFFFFFFFFu << (shift + 8));
#pragma unroll
            for (int i = 0; i < ELEMS; ++i) {
                unsigned int v = val[i];
                if ((v & pmask) == prefix)
                    atomicAdd(&s_wh[wv][(v >> shift) & 0xFF], 1);
            }
            __syncthreads();
            if (tid < 256) {
                int s = 0;
#pragma unroll
                for (int w = 0; w < 16; ++w) s += s_wh[w][tid];
                s_hist[tid] = s;
            }
            __syncthreads();
            if (wv == 0) {
                int c0 = s_hist[4 * lane + 0], c1 = s_hist[4 * lane + 1];
                int c2 = s_hist[4 * lane + 2], c3 = s_hist[4 * lane + 3];
                int t3 = c3, t2 = c2 + t3, t1 = c1 + t2, t0 = c0 + t1;
                int g = t0, G = g;
#pragma unroll
                for (int off = 1; off < 64; off <<= 1) {
                    int o = __shfl_down(G, off);
                    if (lane + off < 64) G += o;
                }
                int above = G - g;
                int suf0 = t0 + above, suf1 = t1 + above;
                int suf2 = t2 + above, suf3 = t3 + above, suf4 = above;
                if (suf0 >= k && suf1 < k) { s_sel = 4 * lane + 0; s_rem = k - suf1; }
                if (suf1 >= k && suf2 < k) { s_sel = 4 * lane + 1; s_rem = k - suf2; }
                if (suf2 >= k && suf3 < k) { s_sel = 4 * lane + 2; s_rem = k - suf3; }
                if (suf3 >= k && suf4 < k) { s_sel = 4 * lane + 3; s_rem = k - suf4; }
            }
            __syncthreads();
            prefix |= ((unsigned int)s_sel) << shift;
            k = s_rem;
        }

        float sgt = 0.0f; int cgt = 0;
#pragma unroll
        for (int i = 0; i < ELEMS; ++i) {
            unsigned int v = val[i];
            if (v > prefix) { sgt += __uint_as_float(v); cgt++; }
        }
#pragma unroll
        for (int off = 32; off > 0; off >>= 1) {
            sgt += __shfl_down(sgt, off);
            cgt += __shfl_down(cgt, off);
        }
        if (lane == 0) { s_sv[wv] = sgt; s_sc[wv] = cgt; }
        __syncthreads();
        if (tid == 0) {
            float S = 0.0f; int Ct = 0;
#pragma unroll
            for (int w = 0; w < 16; ++w) { S += s_sv[w]; Ct += s_sc[w]; }
            negsum_b[b] = S + (float)(nn - Ct) * __uint_as_float(prefix);
        }
    } else {
        if (tid == 0) negsum_b[b] = 0.0f;
    }

#pragma unroll
    for (int off = 32; off > 0; off >>= 1) pce += __shfl_down(pce, off);
    if (lane == 0) s_pv[wv] = pce;
    __syncthreads();
    if (tid == 0) {
        float PCE = 0.0f;
#pragma unroll
        for (int w = 0; w < 16; ++w) PCE += s_pv[w];
        pce_b[b] = PCE;
    }

    // ---- completion protocol: last block performs the final reduction ----
    if (tid == 0) {
        __threadfence();
        int old = atomicAdd(sel_ctr, 1);
        s_last = (old == B_NUM - 1) ? 1 : 0;
    }
    __syncthreads();
    if (s_last) {
        __threadfence();
        float ll = 0.0f, ns = 0.0f, pc = 0.0f; int npos = 0;
        if (tid < B_NUM) {
            ll = loss_l_b[tid];
            ns = negsum_b[tid];
            pc = pce_b[tid];
            npos = num_pos[tid];
        }
#pragma unroll
        for (int off = 32; off > 0; off >>= 1) {
            ll += __shfl_down(ll, off);
            ns += __shfl_down(ns, off);
            pc += __shfl_down(pc, off);
            npos += __shfl_down(npos, off);
        }
        if (lane == 0) {
            ((float*)s_wh[0])[wv] = ll;
            ((float*)s_wh[1])[wv] = ns;
            ((float*)s_wh[2])[wv] = pc;
            s_wh[3][wv] = npos;
        }
        __syncthreads();
        if (tid == 0) {
            float LL = 0.0f, NS = 0.0f, PC = 0.0f; int NP = 0;
#pragma unroll
            for (int w = 0; w < 16; ++w) {
                LL += ((float*)s_wh[0])[w];
                NS += ((float*)s_wh[1])[w];
                PC += ((float*)s_wh[2])[w];
                NP += s_wh[3][w];
            }
            float N = (float)(NP > 1 ? NP : 1);
            out[0] = LL / N;
            out[1] = (PC + NS) / N;
        }
    }
}

// ---------------------------------------------------------------------------
extern "C" void kernel_launch(void* const* d_in, const int* in_sizes, int n_in,
                              void* d_out, int out_size, void* d_ws, size_t ws_size,
                              hipStream_t stream) {
    const float* loc    = (const float*)d_in[0];
    const float* conf   = (const float*)d_in[1];
    const float* priors = (const float*)d_in[2];
    const float* truths = (const float*)d_in[3];
    const int*   labels = (const int*)d_in[4];
    float* out = (float*)d_out;

    int*   ws_i = (int*)d_ws;
    float* ws_f = (float*)d_ws;
    int*   num_pos   = ws_i;                         // [0,64)
    float* loss_l_b  = ws_f + 64;                    // [64,128)
    float* negsum_b  = ws_f + 128;                   // [128,192)
    float* pce_b     = ws_f + 192;                   // [192,256)
    int*   sel_ctr   = ws_i + 256;                   // [256]
    int*   conf_t    = ws_i + 512;                   // [512, 512+BP)
    float* negce     = ws_f + 512 + B_NUM * P_NUM;   // [+BP, +2BP)
    float* lse       = ws_f + 512 + 2 * B_NUM * P_NUM;

    k_fused1<<<GRID1, TPB, 0, stream>>>(loc, conf, priors, truths, labels,
                                        conf_t, num_pos, loss_l_b, lse, negce, sel_ctr);
    k_select<<<B_NUM, 1024, 0, stream>>>(negce, lse, conf, conf_t, num_pos,
                                         loss_l_b, negsum_b, pce_b, sel_ctr, out);
}